// Round 1
// baseline (905.646 us; speedup 1.0000x reference)
//
#include <hip/hip_runtime.h>

#define Vn 200000
#define PADI 199999

// ---------------------------------------------------------------- helpers
__device__ __forceinline__ float2 block_reduce2(float a, float b, float2* red) {
  // 256 threads, 4 waves of 64. Returns (sum_a, sum_b) broadcast to all threads.
  #pragma unroll
  for (int off = 32; off; off >>= 1) { a += __shfl_down(a, off); b += __shfl_down(b, off); }
  __syncthreads();                       // protect red[] reuse across calls
  if ((threadIdx.x & 63) == 0) red[threadIdx.x >> 6] = make_float2(a, b);
  __syncthreads();
  float2 r;
  r.x = red[0].x + red[1].x + red[2].x + red[3].x;
  r.y = red[0].y + red[1].y + red[2].y + red[3].y;
  return r;
}

// ---------------------------------------------------------------- transpose
// out[c*R + r] = in[r*Cfull + c0 + c]   for r in [0,R), c in [0,Ct)
__global__ __launch_bounds__(256) void transpose_kernel(
    const float* __restrict__ in, float* __restrict__ out, int R, int Cfull, int c0, int Ct) {
  int idx = blockIdx.x * 256 + threadIdx.x;
  if (idx >= R * Ct) return;
  int c = idx / R, r = idx - c * R;
  out[idx] = in[(size_t)r * Cfull + c0 + c];
}

// ---------------------------------------------------------------- neighbor encoder
__global__ __launch_bounds__(256) void enc_kernel(
    const float* __restrict__ emb, const float* __restrict__ gcnW, const float* __restrict__ gcnb,
    const float* __restrict__ gateW, const float* __restrict__ gateb,
    const int* __restrict__ knn_tab,
    const int* __restrict__ query, const int* __restrict__ support,
    const int* __restrict__ qlc, const int* __restrict__ qrc,
    const int* __restrict__ slc, const int* __restrict__ src,
    float* __restrict__ query_n, float* __restrict__ supp_n) {
  __shared__ float center[128];
  __shared__ float sims[128];
  __shared__ int kidxs[64];
  __shared__ int sel[32], sel2[32];
  __shared__ int cnt1, cnt2;
  __shared__ float catbuf[256], cat2buf[256];
  __shared__ float part1[256], part2[256];
  __shared__ float structural[128], knnm[128];
  __shared__ float2 red2[4];

  int t = threadIdx.x;
  int g = blockIdx.x;
  int eid; const int* conn; float* outp;
  if (g < 2048)      { eid = query[2*g];                conn = qlc + (size_t)g*256;          outp = query_n + (size_t)g*256; }
  else if (g < 4096) { int b = g-2048; eid = query[2*b+1]; conn = qrc + (size_t)b*256;       outp = query_n + (size_t)b*256 + 128; }
  else if (g < 4101) { int b = g-4096; eid = support[2*b];  conn = slc + (size_t)b*256;      outp = supp_n + (size_t)b*256; }
  else               { int b = g-4101; eid = support[2*b+1]; conn = src + (size_t)b*256;     outp = supp_n + (size_t)b*256 + 128; }
  if (eid < 0 || eid >= Vn) eid = PADI;

  if (t == 0) { cnt1 = 0; cnt2 = 0; }
  if (t < 128) center[t] = emb[(size_t)eid*128 + t];
  if (t >= 128 && t < 192) {
    int kk = knn_tab[(size_t)eid*64 + (t-128)];
    if (kk < 0 || kk >= Vn) kk = PADI;
    kidxs[t-128] = kk;
  }
  __syncthreads();

  int lane = t & 63, wid = t >> 6;
  float cx = center[2*lane], cy = center[2*lane+1];
  // center norm: identical wave-local reduction in each wave (full vector in 64 lanes x2)
  float cn2 = cx*cx + cy*cy;
  #pragma unroll
  for (int off = 32; off; off >>= 1) cn2 += __shfl_down(cn2, off);
  cn2 = __shfl(cn2, 0);
  float cn = fmaxf(sqrtf(cn2), 1e-8f);

  // --- sims for the 128 conn neighbors (wave w handles n = w*32..w*32+31)
  for (int i = 0; i < 32; ++i) {
    int n = wid*32 + i;
    int e2 = conn[2*n + 1];
    float2 x = ((const float2*)(emb + (size_t)e2*128))[lane];
    float d = x.x*cx + x.y*cy;
    float m = x.x*x.x + x.y*x.y;
    #pragma unroll
    for (int off = 32; off; off >>= 1) { d += __shfl_down(d, off); m += __shfl_down(m, off); }
    if (lane == 0) sims[n] = d / (cn * fmaxf(sqrtf(m), 1e-8f));
  }
  __syncthreads();

  // --- top-32 selection (jax.lax.top_k tie-break: lower index wins)
  if (t < 128) {
    float my = sims[t];
    int c = 0;
    for (int j = 0; j < 128; ++j) {
      float sj = sims[j];
      c += (sj > my) || (sj == my && j < t);
    }
    if (c < 32) { int p = atomicAdd(&cnt1, 1); sel[p] = t; }
  }
  __syncthreads();

  // --- mean of selected rel (threads 0..127) and ent (threads 128..255)
  {
    float acc = 0.f;
    if (t < 128) {
      for (int k = 0; k < 32; ++k) { int n = sel[k]; acc += emb[(size_t)conn[2*n]*128 + t]; }
      catbuf[t] = acc * (1.f/32.f);
    } else {
      int i = t - 128;
      for (int k = 0; k < 32; ++k) { int n = sel[k]; acc += emb[(size_t)conn[2*n+1]*128 + i]; }
      catbuf[t] = acc * (1.f/32.f);
    }
  }

  // --- sims for 64 knn candidates (reuse sims[]; safe: no reader after selection sync)
  for (int i = 0; i < 16; ++i) {
    int n = wid*16 + i;
    int e2 = kidxs[n];
    float2 x = ((const float2*)(emb + (size_t)e2*128))[lane];
    float d = x.x*cx + x.y*cy;
    float m = x.x*x.x + x.y*x.y;
    #pragma unroll
    for (int off = 32; off; off >>= 1) { d += __shfl_down(d, off); m += __shfl_down(m, off); }
    if (lane == 0) sims[n] = d / (cn * fmaxf(sqrtf(m), 1e-8f));
  }
  __syncthreads();

  if (t < 64) {
    float my = sims[t];
    int c = 0;
    for (int j = 0; j < 64; ++j) {
      float sj = sims[j];
      c += (sj > my) || (sj == my && j < t);
    }
    if (c < 32) { int p = atomicAdd(&cnt2, 1); sel2[p] = t; }
  }
  __syncthreads();

  if (t < 128) {
    float acc = 0.f;
    for (int k = 0; k < 32; ++k) { int kid = kidxs[sel2[k]]; acc += emb[(size_t)kid*128 + t]; }
    cat2buf[128 + t] = acc * (1.f/32.f);
  } else {
    cat2buf[t - 128] = emb[(size_t)PADI*128 + (t - 128)];   // pad_rel row (zeros by construction)
  }
  __syncthreads();

  // --- joint GCN matvecs: structural & knn_mean share each gcn_W row read
  {
    int i = t & 127, half = t >> 7;
    const float4* w4  = (const float4*)(gcnW + (size_t)i*256 + half*128);
    const float4* c14 = (const float4*)(catbuf + half*128);
    const float4* c24 = (const float4*)(cat2buf + half*128);
    float p1 = 0.f, p2 = 0.f;
    #pragma unroll 8
    for (int j = 0; j < 32; ++j) {
      float4 w = w4[j], a = c14[j], b = c24[j];
      p1 += a.x*w.x + a.y*w.y + a.z*w.z + a.w*w.w;
      p2 += b.x*w.x + b.y*w.y + b.z*w.z + b.w*w.w;
    }
    part1[t] = p1; part2[t] = p2;
  }
  __syncthreads();
  if (t < 128) {
    structural[t] = tanhf(part1[t] + part1[t+128] + gcnb[t]);
    knnm[t]       = tanhf(part2[t] + part2[t+128] + gcnb[t]);
  }
  __syncthreads();

  float gv = (t < 128) ? structural[t]*gateW[t] : knnm[t-128]*gateW[t];
  float2 rr = block_reduce2(gv, 0.f, red2);
  float alpha = 1.f / (1.f + expf(-(rr.x + gateb[0])));
  if (t < 128) outp[t] = (1.f - alpha)*structural[t] + alpha*knnm[t];
}

// ---------------------------------------------------------------- support encoder (5 rows, 1 block)
__global__ __launch_bounds__(256) void supp_kernel(
    const float* __restrict__ supp_n, const float* __restrict__ w1, const float* __restrict__ b1,
    const float* __restrict__ w2, const float* __restrict__ b2,
    const float* __restrict__ g, const float* __restrict__ b,
    float* __restrict__ support_g, float* __restrict__ sg_hat) {
  __shared__ float xs[256];
  __shared__ float hsm[512];
  __shared__ float2 red2[4];
  int t = threadIdx.x;
  float accg = 0.f;
  for (int s = 0; s < 5; ++s) {
    __syncthreads();
    xs[t] = supp_n[s*256 + t];
    __syncthreads();
    #pragma unroll
    for (int uo = 0; uo < 512; uo += 256) {
      int u = uo + t;
      float a = b1[u];
      const float4* w4 = (const float4*)(w1 + (size_t)u*256);
      for (int j4 = 0; j4 < 64; ++j4) {
        float4 wv = w4[j4];
        float4 xv = *(const float4*)&xs[j4*4];
        a += xv.x*wv.x + xv.y*wv.y + xv.z*wv.z + xv.w*wv.w;
      }
      hsm[u] = fmaxf(a, 0.f);
    }
    __syncthreads();
    float v = b2[t] + xs[t];
    const float4* w4 = (const float4*)(w2 + (size_t)t*512);
    for (int u4 = 0; u4 < 128; ++u4) {
      float4 wv = w4[u4];
      float4 hv = *(const float4*)&hsm[u4*4];
      v += hv.x*wv.x + hv.y*wv.y + hv.z*wv.z + hv.w*wv.w;
    }
    float2 sq = block_reduce2(v, v*v, red2);
    float mu  = sq.x * (1.f/256.f);
    float var = sq.y * (1.f/256.f) - mu*mu;
    accg += (v - mu) / sqrtf(var + 1e-5f) * g[t] + b[t];
  }
  float sgv = accg * 0.2f;
  support_g[t] = sgv;
  float2 nn = block_reduce2(sgv*sgv, 0.f, red2);
  sg_hat[t] = sgv / fmaxf(sqrtf(nn.x), 1e-12f);
}

// ---------------------------------------------------------------- z_supp[u] = sum_j sg[j] * Whh[u][256+j]
__global__ __launch_bounds__(256) void zsupp_kernel(
    const float* __restrict__ sg, const float* __restrict__ whh, float* __restrict__ zs) {
  __shared__ float s[256];
  int t = threadIdx.x;
  s[t] = sg[t];
  __syncthreads();
  int u = blockIdx.x * 256 + t;
  const float4* w4 = (const float4*)(whh + (size_t)u*512 + 256);
  float a = 0.f;
  for (int j4 = 0; j4 < 64; ++j4) {
    float4 wv = w4[j4];
    float4 sv = *(const float4*)&s[j4*4];
    a += sv.x*wv.x + sv.y*wv.y + sv.z*wv.z + sv.w*wv.w;
  }
  zs[u] = a;
}

// ---------------------------------------------------------------- support_enc on 2048 rows, 8 rows/block
__global__ __launch_bounds__(256) void qenc_kernel(
    const float* __restrict__ xin, const float* __restrict__ w1t, const float* __restrict__ b1,
    const float* __restrict__ w2t, const float* __restrict__ b2,
    const float* __restrict__ lng, const float* __restrict__ lnb,
    float* __restrict__ xout) {
  __shared__ float xs[8][256];
  __shared__ float hsm[8][512];
  __shared__ float2 red2[4];
  int t = threadIdx.x;
  int r0 = blockIdx.x * 8;
  #pragma unroll
  for (int rr = 0; rr < 8; ++rr) xs[rr][t] = xin[(size_t)(r0+rr)*256 + t];
  __syncthreads();
  // layer 1: hidden 512, coalesced w1t reads, broadcast LDS x reads
  #pragma unroll
  for (int uo = 0; uo < 512; uo += 256) {
    int u = uo + t;
    float bv = b1[u];
    float acc[8];
    #pragma unroll
    for (int rr = 0; rr < 8; ++rr) acc[rr] = bv;
    for (int j4 = 0; j4 < 64; ++j4) {
      float w0 = w1t[(size_t)(j4*4+0)*512 + u];
      float w1v = w1t[(size_t)(j4*4+1)*512 + u];
      float w2v = w1t[(size_t)(j4*4+2)*512 + u];
      float w3 = w1t[(size_t)(j4*4+3)*512 + u];
      #pragma unroll
      for (int rr = 0; rr < 8; ++rr) {
        float4 x = *(const float4*)&xs[rr][j4*4];
        acc[rr] += x.x*w0 + x.y*w1v + x.z*w2v + x.w*w3;
      }
    }
    #pragma unroll
    for (int rr = 0; rr < 8; ++rr) hsm[rr][u] = fmaxf(acc[rr], 0.f);
  }
  __syncthreads();
  // layer 2 + residual
  float val[8];
  {
    float bv = b2[t];
    #pragma unroll
    for (int rr = 0; rr < 8; ++rr) val[rr] = bv + xs[rr][t];
    for (int u4 = 0; u4 < 128; ++u4) {
      float w0 = w2t[(size_t)(u4*4+0)*256 + t];
      float w1v = w2t[(size_t)(u4*4+1)*256 + t];
      float w2v = w2t[(size_t)(u4*4+2)*256 + t];
      float w3 = w2t[(size_t)(u4*4+3)*256 + t];
      #pragma unroll
      for (int rr = 0; rr < 8; ++rr) {
        float4 h4 = *(const float4*)&hsm[rr][u4*4];
        val[rr] += h4.x*w0 + h4.y*w1v + h4.z*w2v + h4.w*w3;
      }
    }
  }
  // layernorm per row
  float gv = lng[t], bv2 = lnb[t];
  for (int rr = 0; rr < 8; ++rr) {
    float2 sq = block_reduce2(val[rr], val[rr]*val[rr], red2);
    float mu  = sq.x * (1.f/256.f);
    float var = sq.y * (1.f/256.f) - mu*mu;
    float rs  = 1.f / sqrtf(var + 1e-5f);
    xout[(size_t)(r0+rr)*256 + t] = (val[rr] - mu) * rs * gv + bv2;
  }
}

// ---------------------------------------------------------------- fp32 GEMM: C = A[M,K]@B[K,N] (+addmat)(+cv1[n])(+cv2[n])
__global__ __launch_bounds__(256) void gemm_kernel(
    const float* __restrict__ A, const float* __restrict__ B, float* __restrict__ C,
    const float* __restrict__ addmat, const float* __restrict__ cv1, const float* __restrict__ cv2,
    int M, int N, int K) {
  __shared__ float As[16][68];   // k-major, padded: 68*4B = 272B rows keep 16B alignment, banks spread
  __shared__ float Bs[16][64];
  int t = threadIdx.x;
  int bx = blockIdx.x, by = blockIdx.y;
  int tx = t & 15, ty = t >> 4;
  float acc[4][4] = {{0.f}};
  int arow = t >> 2, acolq = t & 3;
  int brow = t >> 4, bcol = (t & 15) << 2;
  const float* Arow = A + (size_t)(by*64 + arow)*K;
  const float* Bp   = B + (size_t)brow*N + bx*64 + bcol;

  for (int k0 = 0; k0 < K; k0 += 16) {
    float4 av = ((const float4*)(Arow + k0))[acolq];
    float4 bv = *(const float4*)(Bp + (size_t)k0*N);
    int kc = acolq*4;
    As[kc+0][arow] = av.x;
    As[kc+1][arow] = av.y;
    As[kc+2][arow] = av.z;
    As[kc+3][arow] = av.w;
    *(float4*)&Bs[brow][bcol] = bv;
    __syncthreads();
    #pragma unroll
    for (int kk = 0; kk < 16; ++kk) {
      float4 a = *(const float4*)&As[kk][ty*4];
      float4 b = *(const float4*)&Bs[kk][tx*4];
      acc[0][0] += a.x*b.x; acc[0][1] += a.x*b.y; acc[0][2] += a.x*b.z; acc[0][3] += a.x*b.w;
      acc[1][0] += a.y*b.x; acc[1][1] += a.y*b.y; acc[1][2] += a.y*b.z; acc[1][3] += a.y*b.w;
      acc[2][0] += a.z*b.x; acc[2][1] += a.z*b.y; acc[2][2] += a.z*b.z; acc[2][3] += a.z*b.w;
      acc[3][0] += a.w*b.x; acc[3][1] += a.w*b.y; acc[3][2] += a.w*b.z; acc[3][3] += a.w*b.w;
    }
    __syncthreads();
  }
  int m0 = by*64 + ty*4, n0 = bx*64 + tx*4;
  #pragma unroll
  for (int i = 0; i < 4; ++i) {
    float4 v = make_float4(acc[i][0], acc[i][1], acc[i][2], acc[i][3]);
    size_t off = (size_t)(m0+i)*N + n0;
    if (addmat) { float4 am = *(const float4*)(addmat + off); v.x += am.x; v.y += am.y; v.z += am.z; v.w += am.w; }
    if (cv1)    { float4 cm = *(const float4*)(cv1 + n0);     v.x += cm.x; v.y += cm.y; v.z += cm.z; v.w += cm.w; }
    if (cv2)    { float4 cm = *(const float4*)(cv2 + n0);     v.x += cm.x; v.y += cm.y; v.z += cm.z; v.w += cm.w; }
    *(float4*)(C + off) = v;
  }
}

// ---------------------------------------------------------------- LSTM gates
__global__ __launch_bounds__(256) void gate_kernel(
    const float* __restrict__ Z, const float* __restrict__ qg,
    float* __restrict__ c, float* __restrict__ h, int step0) {
  int idx = blockIdx.x * 256 + threadIdx.x;   // 2048*512
  int r = idx >> 9, j = idx & 511;
  const float* zr = Z + ((size_t)r << 11);
  float zi = zr[j], zf = zr[512 + j], zg = zr[1024 + j];
  float cold = step0 ? 0.f : c[idx];
  float sf = 1.f / (1.f + expf(-zf));
  float si = 1.f / (1.f + expf(-zi));
  float c2 = sf * cold + si * tanhf(zg);
  c[idx] = c2;
  if (j < 256) {
    float zo = zr[1536 + j];
    float so = 1.f / (1.f + expf(-zo));
    h[(size_t)r*256 + j] = qg[(size_t)r*256 + j] + so * tanhf(c2);
  }
}

// ---------------------------------------------------------------- final cosine
__global__ __launch_bounds__(256) void cos_kernel(
    const float* __restrict__ h, const float* __restrict__ sgh, float* __restrict__ out) {
  int wid = threadIdx.x >> 6, lane = threadIdx.x & 63;
  int r = blockIdx.x*4 + wid;
  const float* hr = h + (size_t)r*256;
  float d = 0.f, n2 = 0.f;
  #pragma unroll
  for (int i = 0; i < 4; ++i) {
    float v = hr[lane + i*64];
    d += v * sgh[lane + i*64];
    n2 += v * v;
  }
  #pragma unroll
  for (int off = 32; off; off >>= 1) { d += __shfl_down(d, off); n2 += __shfl_down(n2, off); }
  if (lane == 0) out[r] = d / fmaxf(sqrtf(n2), 1e-12f);
}

// ---------------------------------------------------------------- launch
extern "C" void kernel_launch(void* const* d_in, const int* in_sizes, int n_in,
                              void* d_out, int out_size, void* d_ws, size_t ws_size,
                              hipStream_t stream) {
  const float* emb   = (const float*)d_in[0];
  const float* gcnW  = (const float*)d_in[1];
  const float* gcnb  = (const float*)d_in[2];
  const float* gateW = (const float*)d_in[3];
  const float* gateb = (const float*)d_in[4];
  const float* sew1  = (const float*)d_in[5];
  const float* seb1  = (const float*)d_in[6];
  const float* sew2  = (const float*)d_in[7];
  const float* seb2  = (const float*)d_in[8];
  const float* lng   = (const float*)d_in[9];
  const float* lnb   = (const float*)d_in[10];
  const float* Wih   = (const float*)d_in[11];
  const float* Whh   = (const float*)d_in[12];
  const float* bih   = (const float*)d_in[13];
  const float* bhh   = (const float*)d_in[14];
  const int* query   = (const int*)d_in[15];
  const int* support = (const int*)d_in[16];
  const int* qlc     = (const int*)d_in[17];
  const int* qrc     = (const int*)d_in[19];
  const int* slc     = (const int*)d_in[21];
  const int* src     = (const int*)d_in[23];
  const int* knn     = (const int*)d_in[25];
  float* out = (float*)d_out;

  float* w = (float*)d_ws;
  size_t o = 0;
  auto alloc = [&](size_t n) { float* p = w + o; o += n; return p; };
  float* query_n   = alloc(2048*256);
  float* supp_n    = alloc(5*256 + 192);     // keep 16B-aligned spacing
  float* support_g = alloc(256);
  float* sg_hat    = alloc(256);
  float* z_supp    = alloc(2048);
  float* query_g   = alloc(2048*256);
  float* hbuf      = alloc(2048*256);
  float* cbuf      = alloc(2048*512);
  float* Abuf      = alloc((size_t)2048*2048);
  float* Zbuf      = alloc((size_t)2048*2048);
  float* w1t       = alloc(256*512);
  float* w2t       = alloc(512*256);
  float* wihT      = alloc(256*2048);
  float* whh1T     = alloc(256*2048);
  (void)ws_size; (void)in_sizes; (void)n_in; (void)out_size;

  // weight transposes (re-run each call; ws is re-poisoned by harness)
  transpose_kernel<<<512,  256, 0, stream>>>(sew1, w1t, 512, 256, 0, 256);
  transpose_kernel<<<1024, 256, 0, stream>>>(sew2, w2t, 256, 512, 0, 512);
  transpose_kernel<<<2048, 256, 0, stream>>>(Wih,  wihT, 2048, 256, 0, 256);
  transpose_kernel<<<2048, 256, 0, stream>>>(Whh,  whh1T, 2048, 512, 0, 256);

  // 1) neighbor encoders (q_l, q_r, s_l, s_r)
  enc_kernel<<<4106, 256, 0, stream>>>(emb, gcnW, gcnb, gateW, gateb, knn,
                                       query, support, qlc, qrc, slc, src,
                                       query_n, supp_n);

  // 2) support path
  supp_kernel<<<1, 256, 0, stream>>>(supp_n, sew1, seb1, sew2, seb2, lng, lnb,
                                     support_g, sg_hat);
  zsupp_kernel<<<8, 256, 0, stream>>>(support_g, Whh, z_supp);

  // 3) query encoder MLP+LN
  qenc_kernel<<<256, 256, 0, stream>>>(query_n, w1t, seb1, w2t, seb2, lng, lnb, query_g);

  // 4) LSTM matching: A = qg @ Wih^T + b_ih + b_hh  (step-invariant)
  gemm_kernel<<<dim3(32,32), 256, 0, stream>>>(query_g, wihT, Abuf,
                                               nullptr, bih, bhh, 2048, 2048, 256);
  // step 0: z = A exactly (h_r = 0)
  gate_kernel<<<4096, 256, 0, stream>>>(Abuf, query_g, cbuf, hbuf, 1);
  // steps 1..3: z = h @ Whh[:, :256]^T + A + z_supp
  for (int s = 1; s < 4; ++s) {
    gemm_kernel<<<dim3(32,32), 256, 0, stream>>>(hbuf, whh1T, Zbuf,
                                                 Abuf, z_supp, nullptr, 2048, 2048, 256);
    gate_kernel<<<4096, 256, 0, stream>>>(Zbuf, query_g, cbuf, hbuf, 0);
  }

  // 5) cosine against normalized support_g
  cos_kernel<<<512, 256, 0, stream>>>(hbuf, sg_hat, out);
}

// Round 2
// 778.669 us; speedup vs baseline: 1.1631x; 1.1631x over previous
//
#include <hip/hip_runtime.h>

#define Vn 200000
#define PADI 199999

typedef unsigned short ushort_t;
typedef unsigned int uint_t;
typedef __attribute__((ext_vector_type(8))) short short8;
typedef __attribute__((ext_vector_type(4))) float float4v;

__device__ __forceinline__ float sigm(float x) { return 1.f / (1.f + expf(-x)); }
__device__ __forceinline__ float dot4(float4 a, float4 b) {
  return a.x*b.x + a.y*b.y + a.z*b.z + a.w*b.w;
}
__device__ __forceinline__ ushort_t f2bf(float x) {
  uint_t u = __float_as_uint(x);
  uint_t r = (u + 0x7fffu + ((u >> 16) & 1u)) >> 16;
  return (ushort_t)r;
}
__device__ __forceinline__ float bf2f(ushort_t h) { return __uint_as_float(((uint_t)h) << 16); }

__device__ __forceinline__ float2 block_reduce2(float a, float b, float2* red) {
  #pragma unroll
  for (int off = 32; off; off >>= 1) { a += __shfl_down(a, off); b += __shfl_down(b, off); }
  __syncthreads();
  if ((threadIdx.x & 63) == 0) red[threadIdx.x >> 6] = make_float2(a, b);
  __syncthreads();
  float2 r;
  r.x = red[0].x + red[1].x + red[2].x + red[3].x;
  r.y = red[0].y + red[1].y + red[2].y + red[3].y;
  return r;
}

// ---------------------------------------------------------------- transpose (for qenc weights)
__global__ __launch_bounds__(256) void transpose_kernel(
    const float* __restrict__ in, float* __restrict__ out, int R, int Cfull, int c0, int Ct) {
  int idx = blockIdx.x * 256 + threadIdx.x;
  if (idx >= R * Ct) return;
  int c = idx / R, r = idx - c * R;
  out[idx] = in[(size_t)r * Cfull + c0 + c];
}

// ---------------------------------------------------------------- split preps for bf16-split GEMM
// A2 row layout: [hi(0:256) | lo(256:512) | hi(512:768)]
__global__ __launch_bounds__(256) void split_a_kernel(
    const float* __restrict__ x, ushort_t* __restrict__ a2) {
  int r = blockIdx.x, k = threadIdx.x;
  float v = x[(size_t)r*256 + k];
  ushort_t hi = f2bf(v);
  ushort_t lo = f2bf(v - bf2f(hi));
  ushort_t* row = a2 + (size_t)r*768;
  row[k] = hi; row[256 + k] = lo; row[512 + k] = hi;
}

// B2T row layout: [hi(0:256) | hi(256:512) | lo(512:768)]  (B2T[n] built from W[n][0:256])
__global__ __launch_bounds__(256) void build_b2t_kernel(
    const float* __restrict__ W, ushort_t* __restrict__ b2t, int strideK) {
  int n = blockIdx.x, k = threadIdx.x;
  float v = W[(size_t)n*strideK + k];
  ushort_t hi = f2bf(v);
  ushort_t lo = f2bf(v - bf2f(hi));
  ushort_t* row = b2t + (size_t)n*768;
  row[k] = hi; row[256 + k] = hi; row[512 + k] = lo;
}

__global__ __launch_bounds__(256) void bias_sum_kernel(
    const float* __restrict__ a, const float* __restrict__ b, float* __restrict__ o) {
  int i = blockIdx.x*256 + threadIdx.x;
  o[i] = a[i] + b[i];
}

// ---------------------------------------------------------------- bf16-split MFMA GEMM
// C[m, n] = sum_k A2[m,k]*B2T[n,k]  (K=768) + addmat + cv[n]
// grid: (N/128, M/128), block 256 (4 waves, each a 64x64 quadrant of 16x16 MFMA tiles)
__global__ __launch_bounds__(256) void gemm_bf16_kernel(
    const ushort_t* __restrict__ A2, const ushort_t* __restrict__ B2T,
    float* __restrict__ C, const float* __restrict__ addmat,
    const float* __restrict__ cv, int ldc) {
  __shared__ ushort_t As[128*40];   // row stride 40 shorts (80B): 2-way bank alias only
  __shared__ ushort_t Bs[128*40];
  int t = threadIdx.x;
  int m0 = blockIdx.y * 128, n0 = blockIdx.x * 128;
  int wid = t >> 6, lane = t & 63;
  int wm = (wid >> 1) * 64, wn = (wid & 1) * 64;
  int q = lane >> 4, fr = lane & 15;
  float4v acc[4][4];
  #pragma unroll
  for (int i = 0; i < 4; ++i)
    #pragma unroll
    for (int j = 0; j < 4; ++j) acc[i][j] = (float4v)0.f;

  for (int k0 = 0; k0 < 768; k0 += 32) {
    #pragma unroll
    for (int rnd = 0; rnd < 2; ++rnd) {
      int idx = rnd*256 + t;
      int row = idx >> 2, ch = idx & 3;
      *(short8*)&As[row*40 + ch*8] = *(const short8*)(A2 + (size_t)(m0+row)*768 + k0 + ch*8);
      *(short8*)&Bs[row*40 + ch*8] = *(const short8*)(B2T + (size_t)(n0+row)*768 + k0 + ch*8);
    }
    __syncthreads();
    short8 af[4], bg[4];
    #pragma unroll
    for (int tm = 0; tm < 4; ++tm) af[tm] = *(const short8*)&As[(wm + tm*16 + fr)*40 + q*8];
    #pragma unroll
    for (int tn = 0; tn < 4; ++tn) bg[tn] = *(const short8*)&Bs[(wn + tn*16 + fr)*40 + q*8];
    #pragma unroll
    for (int tm = 0; tm < 4; ++tm)
      #pragma unroll
      for (int tn = 0; tn < 4; ++tn)
        acc[tm][tn] = __builtin_amdgcn_mfma_f32_16x16x32_bf16(af[tm], bg[tn], acc[tm][tn], 0, 0, 0);
    __syncthreads();
  }

  // epilogue: C/D layout col = lane&15, row = q*4 + reg
  #pragma unroll
  for (int tm = 0; tm < 4; ++tm) {
    int gm = m0 + wm + tm*16 + q*4;
    #pragma unroll
    for (int tn = 0; tn < 4; ++tn) {
      int gn = n0 + wn + tn*16 + fr;
      float cvv = cv ? cv[gn] : 0.f;
      #pragma unroll
      for (int reg = 0; reg < 4; ++reg) {
        size_t off = (size_t)(gm + reg) * ldc + gn;
        float x = acc[tm][tn][reg] + cvv;
        if (addmat) x += addmat[off];
        C[off] = x;
      }
    }
  }
}

// ---------------------------------------------------------------- neighbor encoder
__global__ __launch_bounds__(256) void enc_kernel(
    const float* __restrict__ emb, const float* __restrict__ gcnW, const float* __restrict__ gcnb,
    const float* __restrict__ gateW, const float* __restrict__ gateb,
    const int* __restrict__ knn_tab,
    const int* __restrict__ query, const int* __restrict__ support,
    const int* __restrict__ qlc, const int* __restrict__ qrc,
    const int* __restrict__ slc, const int* __restrict__ src,
    float* __restrict__ query_n, float* __restrict__ supp_n) {
  __shared__ float center[128];
  __shared__ float sims[128];
  __shared__ float sims2[64];
  __shared__ int idr[128], ide[128];
  __shared__ int kidxs[64];
  __shared__ int sel[32], sel2[32];
  __shared__ int cnt1, cnt2;
  __shared__ float catbuf[256];
  __shared__ float knnA[128], knnB[128];
  __shared__ float part1[256], part2[256];
  __shared__ float structural[128], knnm[128];
  __shared__ float2 red2[4];

  int t = threadIdx.x;
  int g = blockIdx.x;
  int eid; const int* conn; float* outp;
  if (g < 2048)      { eid = query[2*g];                 conn = qlc + (size_t)g*256;      outp = query_n + (size_t)g*256; }
  else if (g < 4096) { int b = g-2048; eid = query[2*b+1];  conn = qrc + (size_t)b*256;   outp = query_n + (size_t)b*256 + 128; }
  else if (g < 4101) { int b = g-4096; eid = support[2*b];  conn = slc + (size_t)b*256;   outp = supp_n + (size_t)b*256; }
  else               { int b = g-4101; eid = support[2*b+1]; conn = src + (size_t)b*256;  outp = supp_n + (size_t)b*256 + 128; }
  if (eid < 0 || eid >= Vn) eid = PADI;

  if (t == 0) { cnt1 = 0; cnt2 = 0; }
  if (t < 128) {
    int2 cc = ((const int2*)conn)[t];
    idr[t] = cc.x; ide[t] = cc.y;
    center[t] = emb[(size_t)eid*128 + t];
  } else if (t < 192) {
    int kk = knn_tab[(size_t)eid*64 + (t-128)];
    kidxs[t-128] = (kk < 0 || kk >= Vn) ? PADI : kk;
  }
  __syncthreads();

  // 16-lane groups, each handles rows with ILP-2; lane ll covers elems ll*8..ll*8+7
  int gid = t >> 4, ll = t & 15;
  float4 cen0 = *(const float4*)&center[ll*8];
  float4 cen1 = *(const float4*)&center[ll*8 + 4];
  float cn2 = dot4(cen0, cen0) + dot4(cen1, cen1);
  #pragma unroll
  for (int off = 8; off; off >>= 1) cn2 += __shfl_down(cn2, off, 16);
  cn2 = __shfl(cn2, 0, 16);
  float cn = fmaxf(sqrtf(cn2), 1e-8f);

  // conn sims: 4 iters x 16 groups x 2 rows = 128
  #pragma unroll 2
  for (int it = 0; it < 4; ++it) {
    int n0 = it*32 + gid*2;
    int e0 = ide[n0], e1 = ide[n0+1];
    const float4* p0 = (const float4*)(emb + (size_t)e0*128);
    const float4* p1 = (const float4*)(emb + (size_t)e1*128);
    float4 a0 = p0[ll*2], b0 = p0[ll*2+1];
    float4 a1 = p1[ll*2], b1 = p1[ll*2+1];
    float d0 = dot4(a0, cen0) + dot4(b0, cen1), m0 = dot4(a0, a0) + dot4(b0, b0);
    float d1 = dot4(a1, cen0) + dot4(b1, cen1), m1 = dot4(a1, a1) + dot4(b1, b1);
    #pragma unroll
    for (int off = 8; off; off >>= 1) {
      d0 += __shfl_down(d0, off, 16); m0 += __shfl_down(m0, off, 16);
      d1 += __shfl_down(d1, off, 16); m1 += __shfl_down(m1, off, 16);
    }
    if (ll == 0) {
      sims[n0]   = d0 / (cn * fmaxf(sqrtf(m0), 1e-8f));
      sims[n0+1] = d1 / (cn * fmaxf(sqrtf(m1), 1e-8f));
    }
  }
  // knn sims: 2 iters x 16 groups x 2 rows = 64
  #pragma unroll 2
  for (int it = 0; it < 2; ++it) {
    int n0 = it*32 + gid*2;
    int e0 = kidxs[n0], e1 = kidxs[n0+1];
    const float4* p0 = (const float4*)(emb + (size_t)e0*128);
    const float4* p1 = (const float4*)(emb + (size_t)e1*128);
    float4 a0 = p0[ll*2], b0 = p0[ll*2+1];
    float4 a1 = p1[ll*2], b1 = p1[ll*2+1];
    float d0 = dot4(a0, cen0) + dot4(b0, cen1), m0 = dot4(a0, a0) + dot4(b0, b0);
    float d1 = dot4(a1, cen0) + dot4(b1, cen1), m1 = dot4(a1, a1) + dot4(b1, b1);
    #pragma unroll
    for (int off = 8; off; off >>= 1) {
      d0 += __shfl_down(d0, off, 16); m0 += __shfl_down(m0, off, 16);
      d1 += __shfl_down(d1, off, 16); m1 += __shfl_down(m1, off, 16);
    }
    if (ll == 0) {
      sims2[n0]   = d0 / (cn * fmaxf(sqrtf(m0), 1e-8f));
      sims2[n0+1] = d1 / (cn * fmaxf(sqrtf(m1), 1e-8f));
    }
  }
  __syncthreads();

  // top-32 selections (rank count; jax.lax.top_k tie-break: lower index wins)
  if (t < 128) {
    float my = sims[t];
    int c = 0;
    for (int j = 0; j < 128; ++j) {
      float sj = sims[j];
      c += (sj > my) || (sj == my && j < t);
    }
    if (c < 32) { int p = atomicAdd(&cnt1, 1); sel[p] = t; }
  } else if (t < 192) {
    int i = t - 128;
    float my = sims2[i];
    int c = 0;
    for (int j = 0; j < 64; ++j) {
      float sj = sims2[j];
      c += (sj > my) || (sj == my && j < i);
    }
    if (c < 32) { int p = atomicAdd(&cnt2, 1); sel2[p] = i; }
  }
  __syncthreads();

  // gathers: half0 = rel mean + knn k<16 ; half1 = ent mean + knn k>=16
  {
    int i = t & 127;
    float a0 = 0.f, a1 = 0.f, a2 = 0.f, a3 = 0.f;
    float k0 = 0.f, k1 = 0.f;
    if (t < 128) {
      #pragma unroll 2
      for (int k = 0; k < 32; k += 4) {
        a0 += emb[(size_t)idr[sel[k+0]]*128 + i];
        a1 += emb[(size_t)idr[sel[k+1]]*128 + i];
        a2 += emb[(size_t)idr[sel[k+2]]*128 + i];
        a3 += emb[(size_t)idr[sel[k+3]]*128 + i];
      }
      catbuf[i] = (a0+a1+a2+a3) * (1.f/32.f);
      #pragma unroll 2
      for (int k = 0; k < 16; k += 2) {
        k0 += emb[(size_t)kidxs[sel2[k+0]]*128 + i];
        k1 += emb[(size_t)kidxs[sel2[k+1]]*128 + i];
      }
      knnA[i] = k0 + k1;
    } else {
      #pragma unroll 2
      for (int k = 0; k < 32; k += 4) {
        a0 += emb[(size_t)ide[sel[k+0]]*128 + i];
        a1 += emb[(size_t)ide[sel[k+1]]*128 + i];
        a2 += emb[(size_t)ide[sel[k+2]]*128 + i];
        a3 += emb[(size_t)ide[sel[k+3]]*128 + i];
      }
      catbuf[128 + i] = (a0+a1+a2+a3) * (1.f/32.f);
      #pragma unroll 2
      for (int k = 16; k < 32; k += 2) {
        k0 += emb[(size_t)kidxs[sel2[k+0]]*128 + i];
        k1 += emb[(size_t)kidxs[sel2[k+1]]*128 + i];
      }
      knnB[i] = k0 + k1;
    }
  }
  __syncthreads();

  // GCN matvecs. p1: full 256 cols on catbuf. p2: only cols 128..255 (pad_rel half is zero).
  {
    int i = t & 127, half = t >> 7;
    const float4* w1p = (const float4*)(gcnW + (size_t)i*256 + half*128);
    const float4* c1p = (const float4*)(catbuf + half*128);
    float p1 = 0.f;
    #pragma unroll 8
    for (int j = 0; j < 32; ++j) {
      float4 w = w1p[j], a = c1p[j];
      p1 += dot4(w, a);
    }
    const float4* w2p = (const float4*)(gcnW + (size_t)i*256 + 128 + half*64);
    const float4* kap = (const float4*)(knnA + half*64);
    const float4* kbp = (const float4*)(knnB + half*64);
    float p2 = 0.f;
    #pragma unroll 8
    for (int j = 0; j < 16; ++j) {
      float4 w = w2p[j], xa = kap[j], xb = kbp[j];
      float4 s = make_float4(xa.x+xb.x, xa.y+xb.y, xa.z+xb.z, xa.w+xb.w);
      p2 += dot4(w, s);
    }
    part1[t] = p1;
    part2[t] = p2 * (1.f/32.f);
  }
  __syncthreads();
  if (t < 128) {
    structural[t] = tanhf(part1[t] + part1[t+128] + gcnb[t]);
    knnm[t]       = tanhf(part2[t] + part2[t+128] + gcnb[t]);
  }
  __syncthreads();

  float gv = (t < 128) ? structural[t]*gateW[t] : knnm[t-128]*gateW[t];
  float2 rr = block_reduce2(gv, 0.f, red2);
  float alpha = sigm(rr.x + gateb[0]);
  if (t < 128) outp[t] = (1.f - alpha)*structural[t] + alpha*knnm[t];
}

// ---------------------------------------------------------------- support encoder (5 rows)
__global__ __launch_bounds__(256) void supp_kernel(
    const float* __restrict__ supp_n, const float* __restrict__ w1, const float* __restrict__ b1,
    const float* __restrict__ w2, const float* __restrict__ b2,
    const float* __restrict__ g, const float* __restrict__ b,
    float* __restrict__ support_g, float* __restrict__ sg_hat) {
  __shared__ float xs[256];
  __shared__ float hsm[512];
  __shared__ float2 red2[4];
  int t = threadIdx.x;
  float accg = 0.f;
  for (int s = 0; s < 5; ++s) {
    __syncthreads();
    xs[t] = supp_n[s*256 + t];
    __syncthreads();
    #pragma unroll
    for (int uo = 0; uo < 512; uo += 256) {
      int u = uo + t;
      float a = b1[u];
      const float4* w4 = (const float4*)(w1 + (size_t)u*256);
      for (int j4 = 0; j4 < 64; ++j4) {
        float4 wv = w4[j4];
        float4 xv = *(const float4*)&xs[j4*4];
        a += dot4(wv, xv);
      }
      hsm[u] = fmaxf(a, 0.f);
    }
    __syncthreads();
    float v = b2[t] + xs[t];
    const float4* w4 = (const float4*)(w2 + (size_t)t*512);
    for (int u4 = 0; u4 < 128; ++u4) {
      float4 wv = w4[u4];
      float4 hv = *(const float4*)&hsm[u4*4];
      v += dot4(wv, hv);
    }
    float2 sq = block_reduce2(v, v*v, red2);
    float mu  = sq.x * (1.f/256.f);
    float var = sq.y * (1.f/256.f) - mu*mu;
    accg += (v - mu) / sqrtf(var + 1e-5f) * g[t] + b[t];
  }
  float sgv = accg * 0.2f;
  support_g[t] = sgv;
  float2 nn = block_reduce2(sgv*sgv, 0.f, red2);
  sg_hat[t] = sgv / fmaxf(sqrtf(nn.x), 1e-12f);
}

// ---------------------------------------------------------------- z_supp[u] = sum_j sg[j]*Whh[u][256+j], u<1792
__global__ __launch_bounds__(256) void zsupp_kernel(
    const float* __restrict__ sg, const float* __restrict__ whh, float* __restrict__ zs) {
  __shared__ float s[256];
  int t = threadIdx.x;
  s[t] = sg[t];
  __syncthreads();
  int u = blockIdx.x * 256 + t;
  const float4* w4 = (const float4*)(whh + (size_t)u*512 + 256);
  float a = 0.f;
  for (int j4 = 0; j4 < 64; ++j4) {
    float4 wv = w4[j4];
    float4 sv = *(const float4*)&s[j4*4];
    a += dot4(wv, sv);
  }
  zs[u] = a;
}

// ---------------------------------------------------------------- support_enc on 2048 rows, 8 rows/block
__global__ __launch_bounds__(256) void qenc_kernel(
    const float* __restrict__ xin, const float* __restrict__ w1t, const float* __restrict__ b1,
    const float* __restrict__ w2t, const float* __restrict__ b2,
    const float* __restrict__ lng, const float* __restrict__ lnb,
    float* __restrict__ xout) {
  __shared__ float xs[8][256];
  __shared__ float hsm[8][512];
  __shared__ float2 red2[4];
  int t = threadIdx.x;
  int r0 = blockIdx.x * 8;
  #pragma unroll
  for (int rr = 0; rr < 8; ++rr) xs[rr][t] = xin[(size_t)(r0+rr)*256 + t];
  __syncthreads();
  #pragma unroll
  for (int uo = 0; uo < 512; uo += 256) {
    int u = uo + t;
    float bv = b1[u];
    float acc[8];
    #pragma unroll
    for (int rr = 0; rr < 8; ++rr) acc[rr] = bv;
    for (int j4 = 0; j4 < 64; ++j4) {
      float w0 = w1t[(size_t)(j4*4+0)*512 + u];
      float w1v = w1t[(size_t)(j4*4+1)*512 + u];
      float w2v = w1t[(size_t)(j4*4+2)*512 + u];
      float w3 = w1t[(size_t)(j4*4+3)*512 + u];
      #pragma unroll
      for (int rr = 0; rr < 8; ++rr) {
        float4 x = *(const float4*)&xs[rr][j4*4];
        acc[rr] += x.x*w0 + x.y*w1v + x.z*w2v + x.w*w3;
      }
    }
    #pragma unroll
    for (int rr = 0; rr < 8; ++rr) hsm[rr][u] = fmaxf(acc[rr], 0.f);
  }
  __syncthreads();
  float val[8];
  {
    float bv = b2[t];
    #pragma unroll
    for (int rr = 0; rr < 8; ++rr) val[rr] = bv + xs[rr][t];
    for (int u4 = 0; u4 < 128; ++u4) {
      float w0 = w2t[(size_t)(u4*4+0)*256 + t];
      float w1v = w2t[(size_t)(u4*4+1)*256 + t];
      float w2v = w2t[(size_t)(u4*4+2)*256 + t];
      float w3 = w2t[(size_t)(u4*4+3)*256 + t];
      #pragma unroll
      for (int rr = 0; rr < 8; ++rr) {
        float4 h4 = *(const float4*)&hsm[rr][u4*4];
        val[rr] += h4.x*w0 + h4.y*w1v + h4.z*w2v + h4.w*w3;
      }
    }
  }
  float gv = lng[t], bv2 = lnb[t];
  for (int rr = 0; rr < 8; ++rr) {
    float2 sq = block_reduce2(val[rr], val[rr]*val[rr], red2);
    float mu  = sq.x * (1.f/256.f);
    float var = sq.y * (1.f/256.f) - mu*mu;
    float rs  = 1.f / sqrtf(var + 1e-5f);
    xout[(size_t)(r0+rr)*256 + t] = (val[rr] - mu) * rs * gv + bv2;
  }
}

// ---------------------------------------------------------------- LSTM gates (Z stride 1792)
__global__ __launch_bounds__(256) void gate_kernel(
    const float* __restrict__ Z, const float* __restrict__ qg,
    float* __restrict__ c, float* __restrict__ h, int step0) {
  int idx = blockIdx.x * 256 + threadIdx.x;   // 2048*512
  int r = idx >> 9, j = idx & 511;
  const float* zr = Z + (size_t)r * 1792;
  float zi = zr[j], zf = zr[512 + j], zg = zr[1024 + j];
  float cold = step0 ? 0.f : c[idx];
  float c2 = sigm(zf) * cold + sigm(zi) * tanhf(zg);
  c[idx] = c2;
  if (j < 256) {
    float zo = zr[1536 + j];
    h[(size_t)r*256 + j] = qg[(size_t)r*256 + j] + sigm(zo) * tanhf(c2);
  }
}

// ---------------------------------------------------------------- final gate + cosine fused
__global__ __launch_bounds__(256) void gatecos_kernel(
    const float* __restrict__ Z, const float* __restrict__ qg, const float* __restrict__ c,
    const float* __restrict__ sgh, float* __restrict__ out) {
  int wid = threadIdx.x >> 6, lane = threadIdx.x & 63;
  int r = blockIdx.x*4 + wid;
  const float* zr = Z + (size_t)r * 1792;
  float d = 0.f, n2 = 0.f;
  #pragma unroll
  for (int i = 0; i < 4; ++i) {
    int j = lane + i*64;
    float zi = zr[j], zf = zr[512 + j], zg = zr[1024 + j], zo = zr[1536 + j];
    float cold = c[(size_t)r*512 + j];
    float c2 = sigm(zf) * cold + sigm(zi) * tanhf(zg);
    float h = qg[(size_t)r*256 + j] + sigm(zo) * tanhf(c2);
    d += h * sgh[j];
    n2 += h * h;
  }
  #pragma unroll
  for (int off = 32; off; off >>= 1) { d += __shfl_down(d, off); n2 += __shfl_down(n2, off); }
  if (lane == 0) out[r] = d / fmaxf(sqrtf(n2), 1e-12f);
}

// ---------------------------------------------------------------- launch
extern "C" void kernel_launch(void* const* d_in, const int* in_sizes, int n_in,
                              void* d_out, int out_size, void* d_ws, size_t ws_size,
                              hipStream_t stream) {
  const float* emb   = (const float*)d_in[0];
  const float* gcnW  = (const float*)d_in[1];
  const float* gcnb  = (const float*)d_in[2];
  const float* gateW = (const float*)d_in[3];
  const float* gateb = (const float*)d_in[4];
  const float* sew1  = (const float*)d_in[5];
  const float* seb1  = (const float*)d_in[6];
  const float* sew2  = (const float*)d_in[7];
  const float* seb2  = (const float*)d_in[8];
  const float* lng   = (const float*)d_in[9];
  const float* lnb   = (const float*)d_in[10];
  const float* Wih   = (const float*)d_in[11];
  const float* Whh   = (const float*)d_in[12];
  const float* bih   = (const float*)d_in[13];
  const float* bhh   = (const float*)d_in[14];
  const int* query   = (const int*)d_in[15];
  const int* support = (const int*)d_in[16];
  const int* qlc     = (const int*)d_in[17];
  const int* qrc     = (const int*)d_in[19];
  const int* slc     = (const int*)d_in[21];
  const int* src     = (const int*)d_in[23];
  const int* knn     = (const int*)d_in[25];
  float* out = (float*)d_out;

  float* w = (float*)d_ws;
  size_t o = 0;
  auto alloc = [&](size_t n) { float* p = w + o; o += (n + 15) & ~(size_t)15; return p; };
  float* query_n   = alloc(2048*256);
  float* supp_n    = alloc(5*256);
  float* support_g = alloc(256);
  float* sg_hat    = alloc(256);
  float* z_supp    = alloc(1792);
  float* query_g   = alloc(2048*256);
  float* hbuf      = alloc(2048*256);
  float* cbuf      = alloc(2048*512);
  float* Abuf      = alloc((size_t)2048*1792);
  float* Zbuf      = alloc((size_t)2048*1792);
  float* w1t       = alloc(256*512);
  float* w2t       = alloc(512*256);
  float* bias_s    = alloc(1792);
  ushort_t* A2     = (ushort_t*)alloc((size_t)2048*768/2);
  ushort_t* B2ih   = (ushort_t*)alloc((size_t)1792*768/2);
  ushort_t* B2hh   = (ushort_t*)alloc((size_t)1792*768/2);
  (void)ws_size; (void)in_sizes; (void)n_in; (void)out_size;

  // prep: weight transposes + bf16 splits + bias sum
  transpose_kernel<<<512,  256, 0, stream>>>(sew1, w1t, 512, 256, 0, 256);
  transpose_kernel<<<1024, 256, 0, stream>>>(sew2, w2t, 256, 512, 0, 512);
  build_b2t_kernel<<<1792, 256, 0, stream>>>(Wih, B2ih, 256);
  build_b2t_kernel<<<1792, 256, 0, stream>>>(Whh, B2hh, 512);
  bias_sum_kernel<<<7, 256, 0, stream>>>(bih, bhh, bias_s);

  // 1) neighbor encoders
  enc_kernel<<<4106, 256, 0, stream>>>(emb, gcnW, gcnb, gateW, gateb, knn,
                                       query, support, qlc, qrc, slc, src,
                                       query_n, supp_n);

  // 2) support path
  supp_kernel<<<1, 256, 0, stream>>>(supp_n, sew1, seb1, sew2, seb2, lng, lnb,
                                     support_g, sg_hat);
  zsupp_kernel<<<7, 256, 0, stream>>>(support_g, Whh, z_supp);

  // 3) query encoder MLP+LN
  qenc_kernel<<<256, 256, 0, stream>>>(query_n, w1t, seb1, w2t, seb2, lng, lnb, query_g);

  // 4) LSTM matching with split-bf16 MFMA GEMMs (N=1792: o-gate tail columns unused)
  split_a_kernel<<<2048, 256, 0, stream>>>(query_g, A2);
  gemm_bf16_kernel<<<dim3(14,16), 256, 0, stream>>>(A2, B2ih, Abuf, nullptr, bias_s, 1792);
  gate_kernel<<<4096, 256, 0, stream>>>(Abuf, query_g, cbuf, hbuf, 1);
  for (int s = 1; s < 4; ++s) {
    split_a_kernel<<<2048, 256, 0, stream>>>(hbuf, A2);
    gemm_bf16_kernel<<<dim3(14,16), 256, 0, stream>>>(A2, B2hh, Zbuf, Abuf, z_supp, 1792);
    if (s < 3) gate_kernel<<<4096, 256, 0, stream>>>(Zbuf, query_g, cbuf, hbuf, 0);
    else       gatecos_kernel<<<512, 256, 0, stream>>>(Zbuf, query_g, cbuf, sg_hat, out);
  }
}

// Round 3
// 581.827 us; speedup vs baseline: 1.5566x; 1.3383x over previous
//
#include <hip/hip_runtime.h>

#define Vn 200000
#define PADI 199999

typedef unsigned short ushort_t;
typedef unsigned int uint_t;
typedef __attribute__((ext_vector_type(8))) short short8;
typedef __attribute__((ext_vector_type(4))) float float4v;

__device__ __forceinline__ float sigm(float x) { return 1.f / (1.f + expf(-x)); }
__device__ __forceinline__ float dot4(float4 a, float4 b) {
  return a.x*b.x + a.y*b.y + a.z*b.z + a.w*b.w;
}
__device__ __forceinline__ ushort_t f2bf(float x) {
  uint_t u = __float_as_uint(x);
  uint_t r = (u + 0x7fffu + ((u >> 16) & 1u)) >> 16;
  return (ushort_t)r;
}
__device__ __forceinline__ float bf2f(ushort_t h) { return __uint_as_float(((uint_t)h) << 16); }

__device__ __forceinline__ float2 block_reduce2(float a, float b, float2* red) {
  #pragma unroll
  for (int off = 32; off; off >>= 1) { a += __shfl_down(a, off); b += __shfl_down(b, off); }
  __syncthreads();
  if ((threadIdx.x & 63) == 0) red[threadIdx.x >> 6] = make_float2(a, b);
  __syncthreads();
  float2 r;
  r.x = red[0].x + red[1].x + red[2].x + red[3].x;
  r.y = red[0].y + red[1].y + red[2].y + red[3].y;
  return r;
}

// ---------------------------------------------------------------- transpose (for qenc weights)
__global__ __launch_bounds__(256) void transpose_kernel(
    const float* __restrict__ in, float* __restrict__ out, int R, int Cfull, int c0, int Ct) {
  int idx = blockIdx.x * 256 + threadIdx.x;
  if (idx >= R * Ct) return;
  int c = idx / R, r = idx - c * R;
  out[idx] = in[(size_t)r * Cfull + c0 + c];
}

// ---------------------------------------------------------------- B2T split prep
// B2T row layout: [hi(0:256) | hi(256:512) | lo(512:768)]  (built from W[n][0:256])
__global__ __launch_bounds__(256) void build_b2t_kernel(
    const float* __restrict__ W, ushort_t* __restrict__ b2t, int strideK) {
  int n = blockIdx.x, k = threadIdx.x;
  float v = W[(size_t)n*strideK + k];
  ushort_t hi = f2bf(v);
  ushort_t lo = f2bf(v - bf2f(hi));
  ushort_t* row = b2t + (size_t)n*768;
  row[k] = hi; row[256 + k] = hi; row[512 + k] = lo;
}

__global__ __launch_bounds__(256) void bias_sum_kernel(
    const float* __restrict__ a, const float* __restrict__ b, float* __restrict__ o) {
  int i = blockIdx.x*256 + threadIdx.x;
  o[i] = a[i] + b[i];
}

// ---------------------------------------------------------------- bf16-split MFMA GEMM
// C[m, n] = sum_k A2[m,k]*B2T[n,k]  (K=768) + addmat + cv[n]
__global__ __launch_bounds__(256) void gemm_bf16_kernel(
    const ushort_t* __restrict__ A2, const ushort_t* __restrict__ B2T,
    float* __restrict__ C, const float* __restrict__ addmat,
    const float* __restrict__ cv, int ldc) {
  __shared__ ushort_t As[128*40];
  __shared__ ushort_t Bs[128*40];
  int t = threadIdx.x;
  int m0 = blockIdx.y * 128, n0 = blockIdx.x * 128;
  int wid = t >> 6, lane = t & 63;
  int wm = (wid >> 1) * 64, wn = (wid & 1) * 64;
  int q = lane >> 4, fr = lane & 15;
  float4v acc[4][4];
  #pragma unroll
  for (int i = 0; i < 4; ++i)
    #pragma unroll
    for (int j = 0; j < 4; ++j) acc[i][j] = (float4v)0.f;

  for (int k0 = 0; k0 < 768; k0 += 32) {
    #pragma unroll
    for (int rnd = 0; rnd < 2; ++rnd) {
      int idx = rnd*256 + t;
      int row = idx >> 2, ch = idx & 3;
      *(short8*)&As[row*40 + ch*8] = *(const short8*)(A2 + (size_t)(m0+row)*768 + k0 + ch*8);
      *(short8*)&Bs[row*40 + ch*8] = *(const short8*)(B2T + (size_t)(n0+row)*768 + k0 + ch*8);
    }
    __syncthreads();
    short8 af[4], bg[4];
    #pragma unroll
    for (int tm = 0; tm < 4; ++tm) af[tm] = *(const short8*)&As[(wm + tm*16 + fr)*40 + q*8];
    #pragma unroll
    for (int tn = 0; tn < 4; ++tn) bg[tn] = *(const short8*)&Bs[(wn + tn*16 + fr)*40 + q*8];
    #pragma unroll
    for (int tm = 0; tm < 4; ++tm)
      #pragma unroll
      for (int tn = 0; tn < 4; ++tn)
        acc[tm][tn] = __builtin_amdgcn_mfma_f32_16x16x32_bf16(af[tm], bg[tn], acc[tm][tn], 0, 0, 0);
    __syncthreads();
  }

  #pragma unroll
  for (int tm = 0; tm < 4; ++tm) {
    int gm = m0 + wm + tm*16 + q*4;
    #pragma unroll
    for (int tn = 0; tn < 4; ++tn) {
      int gn = n0 + wn + tn*16 + fr;
      float cvv = cv ? cv[gn] : 0.f;
      #pragma unroll
      for (int reg = 0; reg < 4; ++reg) {
        size_t off = (size_t)(gm + reg) * ldc + gn;
        float x = acc[tm][tn][reg] + cvv;
        if (addmat) x += addmat[off];
        C[off] = x;
      }
    }
  }
}

// ---------------------------------------------------------------- neighbor encoder
__global__ __launch_bounds__(256) void enc_kernel(
    const float* __restrict__ emb, const float* __restrict__ gcnW, const float* __restrict__ gcnb,
    const float* __restrict__ gateW, const float* __restrict__ gateb,
    const int* __restrict__ knn_tab,
    const int* __restrict__ query, const int* __restrict__ support,
    const int* __restrict__ qlc, const int* __restrict__ qrc,
    const int* __restrict__ slc, const int* __restrict__ src,
    float* __restrict__ xbuf) {   // 2056 x 256; support rows at 2048..2052
  __shared__ float center[128];
  __shared__ float sims[128];
  __shared__ float sims2[64];
  __shared__ int idr[128], ide[128];
  __shared__ int kidxs[64];
  __shared__ int sel[32], sel2[32];
  __shared__ int cnt1, cnt2;
  __shared__ float catbuf[256];
  __shared__ float knnA[128], knnB[128];
  __shared__ float part1[256], part2[256];
  __shared__ float structural[128], knnm[128];
  __shared__ float2 red2[4];

  int t = threadIdx.x;
  int g = blockIdx.x;
  int eid; const int* conn; float* outp;
  if (g < 2048)      { eid = query[2*g];                 conn = qlc + (size_t)g*256;      outp = xbuf + (size_t)g*256; }
  else if (g < 4096) { int b = g-2048; eid = query[2*b+1];  conn = qrc + (size_t)b*256;   outp = xbuf + (size_t)b*256 + 128; }
  else if (g < 4101) { int b = g-4096; eid = support[2*b];  conn = slc + (size_t)b*256;   outp = xbuf + (size_t)(2048+b)*256; }
  else               { int b = g-4101; eid = support[2*b+1]; conn = src + (size_t)b*256;  outp = xbuf + (size_t)(2048+b)*256 + 128; }
  if (eid < 0 || eid >= Vn) eid = PADI;

  if (t == 0) { cnt1 = 0; cnt2 = 0; }
  if (t < 128) {
    int2 cc = ((const int2*)conn)[t];
    idr[t] = cc.x; ide[t] = cc.y;
    center[t] = emb[(size_t)eid*128 + t];
  } else if (t < 192) {
    int kk = knn_tab[(size_t)eid*64 + (t-128)];
    kidxs[t-128] = (kk < 0 || kk >= Vn) ? PADI : kk;
  }
  __syncthreads();

  int gid = t >> 4, ll = t & 15;
  float4 cen0 = *(const float4*)&center[ll*8];
  float4 cen1 = *(const float4*)&center[ll*8 + 4];
  float cn2 = dot4(cen0, cen0) + dot4(cen1, cen1);
  #pragma unroll
  for (int off = 8; off; off >>= 1) cn2 += __shfl_down(cn2, off, 16);
  cn2 = __shfl(cn2, 0, 16);
  float cn = fmaxf(sqrtf(cn2), 1e-8f);

  #pragma unroll 2
  for (int it = 0; it < 4; ++it) {
    int n0 = it*32 + gid*2;
    int e0 = ide[n0], e1 = ide[n0+1];
    const float4* p0 = (const float4*)(emb + (size_t)e0*128);
    const float4* p1 = (const float4*)(emb + (size_t)e1*128);
    float4 a0 = p0[ll*2], b0 = p0[ll*2+1];
    float4 a1 = p1[ll*2], b1 = p1[ll*2+1];
    float d0 = dot4(a0, cen0) + dot4(b0, cen1), m0 = dot4(a0, a0) + dot4(b0, b0);
    float d1 = dot4(a1, cen0) + dot4(b1, cen1), m1 = dot4(a1, a1) + dot4(b1, b1);
    #pragma unroll
    for (int off = 8; off; off >>= 1) {
      d0 += __shfl_down(d0, off, 16); m0 += __shfl_down(m0, off, 16);
      d1 += __shfl_down(d1, off, 16); m1 += __shfl_down(m1, off, 16);
    }
    if (ll == 0) {
      sims[n0]   = d0 / (cn * fmaxf(sqrtf(m0), 1e-8f));
      sims[n0+1] = d1 / (cn * fmaxf(sqrtf(m1), 1e-8f));
    }
  }
  #pragma unroll 2
  for (int it = 0; it < 2; ++it) {
    int n0 = it*32 + gid*2;
    int e0 = kidxs[n0], e1 = kidxs[n0+1];
    const float4* p0 = (const float4*)(emb + (size_t)e0*128);
    const float4* p1 = (const float4*)(emb + (size_t)e1*128);
    float4 a0 = p0[ll*2], b0 = p0[ll*2+1];
    float4 a1 = p1[ll*2], b1 = p1[ll*2+1];
    float d0 = dot4(a0, cen0) + dot4(b0, cen1), m0 = dot4(a0, a0) + dot4(b0, b0);
    float d1 = dot4(a1, cen0) + dot4(b1, cen1), m1 = dot4(a1, a1) + dot4(b1, b1);
    #pragma unroll
    for (int off = 8; off; off >>= 1) {
      d0 += __shfl_down(d0, off, 16); m0 += __shfl_down(m0, off, 16);
      d1 += __shfl_down(d1, off, 16); m1 += __shfl_down(m1, off, 16);
    }
    if (ll == 0) {
      sims2[n0]   = d0 / (cn * fmaxf(sqrtf(m0), 1e-8f));
      sims2[n0+1] = d1 / (cn * fmaxf(sqrtf(m1), 1e-8f));
    }
  }
  __syncthreads();

  if (t < 128) {
    float my = sims[t];
    int c = 0;
    for (int j = 0; j < 128; ++j) {
      float sj = sims[j];
      c += (sj > my) || (sj == my && j < t);
    }
    if (c < 32) { int p = atomicAdd(&cnt1, 1); sel[p] = t; }
  } else if (t < 192) {
    int i = t - 128;
    float my = sims2[i];
    int c = 0;
    for (int j = 0; j < 64; ++j) {
      float sj = sims2[j];
      c += (sj > my) || (sj == my && j < i);
    }
    if (c < 32) { int p = atomicAdd(&cnt2, 1); sel2[p] = i; }
  }
  __syncthreads();

  {
    int i = t & 127;
    float a0 = 0.f, a1 = 0.f, a2 = 0.f, a3 = 0.f;
    float k0 = 0.f, k1 = 0.f;
    if (t < 128) {
      #pragma unroll 2
      for (int k = 0; k < 32; k += 4) {
        a0 += emb[(size_t)idr[sel[k+0]]*128 + i];
        a1 += emb[(size_t)idr[sel[k+1]]*128 + i];
        a2 += emb[(size_t)idr[sel[k+2]]*128 + i];
        a3 += emb[(size_t)idr[sel[k+3]]*128 + i];
      }
      catbuf[i] = (a0+a1+a2+a3) * (1.f/32.f);
      #pragma unroll 2
      for (int k = 0; k < 16; k += 2) {
        k0 += emb[(size_t)kidxs[sel2[k+0]]*128 + i];
        k1 += emb[(size_t)kidxs[sel2[k+1]]*128 + i];
      }
      knnA[i] = k0 + k1;
    } else {
      #pragma unroll 2
      for (int k = 0; k < 32; k += 4) {
        a0 += emb[(size_t)ide[sel[k+0]]*128 + i];
        a1 += emb[(size_t)ide[sel[k+1]]*128 + i];
        a2 += emb[(size_t)ide[sel[k+2]]*128 + i];
        a3 += emb[(size_t)ide[sel[k+3]]*128 + i];
      }
      catbuf[128 + i] = (a0+a1+a2+a3) * (1.f/32.f);
      #pragma unroll 2
      for (int k = 16; k < 32; k += 2) {
        k0 += emb[(size_t)kidxs[sel2[k+0]]*128 + i];
        k1 += emb[(size_t)kidxs[sel2[k+1]]*128 + i];
      }
      knnB[i] = k0 + k1;
    }
  }
  __syncthreads();

  {
    int i = t & 127, half = t >> 7;
    const float4* w1p = (const float4*)(gcnW + (size_t)i*256 + half*128);
    const float4* c1p = (const float4*)(catbuf + half*128);
    float p1 = 0.f;
    #pragma unroll 8
    for (int j = 0; j < 32; ++j) {
      float4 w = w1p[j], a = c1p[j];
      p1 += dot4(w, a);
    }
    const float4* w2p = (const float4*)(gcnW + (size_t)i*256 + 128 + half*64);
    const float4* kap = (const float4*)(knnA + half*64);
    const float4* kbp = (const float4*)(knnB + half*64);
    float p2 = 0.f;
    #pragma unroll 8
    for (int j = 0; j < 16; ++j) {
      float4 w = w2p[j], xa = kap[j], xb = kbp[j];
      float4 s = make_float4(xa.x+xb.x, xa.y+xb.y, xa.z+xb.z, xa.w+xb.w);
      p2 += dot4(w, s);
    }
    part1[t] = p1;
    part2[t] = p2 * (1.f/32.f);
  }
  __syncthreads();
  if (t < 128) {
    structural[t] = tanhf(part1[t] + part1[t+128] + gcnb[t]);
    knnm[t]       = tanhf(part2[t] + part2[t+128] + gcnb[t]);
  }
  __syncthreads();

  float gv = (t < 128) ? structural[t]*gateW[t] : knnm[t-128]*gateW[t];
  float2 rr = block_reduce2(gv, 0.f, red2);
  float alpha = sigm(rr.x + gateb[0]);
  if (t < 128) outp[t] = (1.f - alpha)*structural[t] + alpha*knnm[t];
}

// ---------------------------------------------------------------- support_enc MLP+LN, 8 rows/block
// also emits split-bf16 A2 rows for rows < 2048
__global__ __launch_bounds__(256) void qenc_kernel(
    const float* __restrict__ xin, const float* __restrict__ w1t, const float* __restrict__ b1,
    const float* __restrict__ w2t, const float* __restrict__ b2,
    const float* __restrict__ lng, const float* __restrict__ lnb,
    float* __restrict__ xout, ushort_t* __restrict__ a2) {
  __shared__ float xs[8][256];
  __shared__ float hsm[8][512];
  __shared__ float2 red2[4];
  int t = threadIdx.x;
  int r0 = blockIdx.x * 8;
  #pragma unroll
  for (int rr = 0; rr < 8; ++rr) xs[rr][t] = xin[(size_t)(r0+rr)*256 + t];
  __syncthreads();
  #pragma unroll
  for (int uo = 0; uo < 512; uo += 256) {
    int u = uo + t;
    float bv = b1[u];
    float acc[8];
    #pragma unroll
    for (int rr = 0; rr < 8; ++rr) acc[rr] = bv;
    for (int j4 = 0; j4 < 64; ++j4) {
      float w0 = w1t[(size_t)(j4*4+0)*512 + u];
      float w1v = w1t[(size_t)(j4*4+1)*512 + u];
      float w2v = w1t[(size_t)(j4*4+2)*512 + u];
      float w3 = w1t[(size_t)(j4*4+3)*512 + u];
      #pragma unroll
      for (int rr = 0; rr < 8; ++rr) {
        float4 x = *(const float4*)&xs[rr][j4*4];
        acc[rr] += x.x*w0 + x.y*w1v + x.z*w2v + x.w*w3;
      }
    }
    #pragma unroll
    for (int rr = 0; rr < 8; ++rr) hsm[rr][u] = fmaxf(acc[rr], 0.f);
  }
  __syncthreads();
  float val[8];
  {
    float bv = b2[t];
    #pragma unroll
    for (int rr = 0; rr < 8; ++rr) val[rr] = bv + xs[rr][t];
    for (int u4 = 0; u4 < 128; ++u4) {
      float w0 = w2t[(size_t)(u4*4+0)*256 + t];
      float w1v = w2t[(size_t)(u4*4+1)*256 + t];
      float w2v = w2t[(size_t)(u4*4+2)*256 + t];
      float w3 = w2t[(size_t)(u4*4+3)*256 + t];
      #pragma unroll
      for (int rr = 0; rr < 8; ++rr) {
        float4 h4 = *(const float4*)&hsm[rr][u4*4];
        val[rr] += h4.x*w0 + h4.y*w1v + h4.z*w2v + h4.w*w3;
      }
    }
  }
  float gv = lng[t], bv2 = lnb[t];
  for (int rr = 0; rr < 8; ++rr) {
    int r = r0 + rr;
    float2 sq = block_reduce2(val[rr], val[rr]*val[rr], red2);
    float mu  = sq.x * (1.f/256.f);
    float var = sq.y * (1.f/256.f) - mu*mu;
    float rs  = 1.f / sqrtf(var + 1e-5f);
    float ov  = (val[rr] - mu) * rs * gv + bv2;
    xout[(size_t)r*256 + t] = ov;
    if (r < 2048) {
      ushort_t hi = f2bf(ov);
      ushort_t lo = f2bf(ov - bf2f(hi));
      ushort_t* row = a2 + (size_t)r*768;
      row[t] = hi; row[256 + t] = lo; row[512 + t] = hi;
    }
  }
}

// ---------------------------------------------------------------- finalize: sg_hat + z_supp
__global__ __launch_bounds__(256) void finalize_kernel(
    const float* __restrict__ qout, const float* __restrict__ whh,
    float* __restrict__ sg_hat, float* __restrict__ z_supp) {
  __shared__ float sg[256];
  __shared__ float2 red2[4];
  int t = threadIdx.x;
  float acc = 0.f;
  #pragma unroll
  for (int s = 0; s < 5; ++s) acc += qout[(size_t)(2048+s)*256 + t];
  float sgv = acc * 0.2f;
  sg[t] = sgv;
  float2 nn = block_reduce2(sgv*sgv, 0.f, red2);
  if (blockIdx.x == 0) sg_hat[t] = sgv / fmaxf(sqrtf(nn.x), 1e-12f);
  __syncthreads();
  int u = blockIdx.x*256 + t;
  const float4* w4 = (const float4*)(whh + (size_t)u*512 + 256);
  float a = 0.f;
  #pragma unroll 4
  for (int j4 = 0; j4 < 64; ++j4) {
    float4 wv = w4[j4];
    float4 sv = *(const float4*)&sg[j4*4];
    a += dot4(wv, sv);
  }
  z_supp[u] = a;
}

// ---------------------------------------------------------------- LSTM gates (Z stride 1792), writes split A2
__global__ __launch_bounds__(256) void gate_kernel(
    const float* __restrict__ Z, const float* __restrict__ qg,
    float* __restrict__ c, ushort_t* __restrict__ a2, int step0) {
  int idx = blockIdx.x * 256 + threadIdx.x;   // 2048*512
  int r = idx >> 9, j = idx & 511;
  const float* zr = Z + (size_t)r * 1792;
  float zi = zr[j], zf = zr[512 + j], zg = zr[1024 + j];
  float cold = step0 ? 0.f : c[idx];
  float c2 = sigm(zf) * cold + sigm(zi) * tanhf(zg);
  c[idx] = c2;
  if (j < 256) {
    float zo = zr[1536 + j];
    float h = qg[(size_t)r*256 + j] + sigm(zo) * tanhf(c2);
    ushort_t hi = f2bf(h);
    ushort_t lo = f2bf(h - bf2f(hi));
    ushort_t* row = a2 + (size_t)r*768;
    row[j] = hi; row[256 + j] = lo; row[512 + j] = hi;
  }
}

// ---------------------------------------------------------------- final gate + cosine fused
__global__ __launch_bounds__(256) void gatecos_kernel(
    const float* __restrict__ Z, const float* __restrict__ qg, const float* __restrict__ c,
    const float* __restrict__ sgh, float* __restrict__ out) {
  int wid = threadIdx.x >> 6, lane = threadIdx.x & 63;
  int r = blockIdx.x*4 + wid;
  const float* zr = Z + (size_t)r * 1792;
  float d = 0.f, n2 = 0.f;
  #pragma unroll
  for (int i = 0; i < 4; ++i) {
    int j = lane + i*64;
    float zi = zr[j], zf = zr[512 + j], zg = zr[1024 + j], zo = zr[1536 + j];
    float cold = c[(size_t)r*512 + j];
    float c2 = sigm(zf) * cold + sigm(zi) * tanhf(zg);
    float h = qg[(size_t)r*256 + j] + sigm(zo) * tanhf(c2);
    d += h * sgh[j];
    n2 += h * h;
  }
  #pragma unroll
  for (int off = 32; off; off >>= 1) { d += __shfl_down(d, off); n2 += __shfl_down(n2, off); }
  if (lane == 0) out[r] = d / fmaxf(sqrtf(n2), 1e-12f);
}

// ---------------------------------------------------------------- launch
extern "C" void kernel_launch(void* const* d_in, const int* in_sizes, int n_in,
                              void* d_out, int out_size, void* d_ws, size_t ws_size,
                              hipStream_t stream) {
  const float* emb   = (const float*)d_in[0];
  const float* gcnW  = (const float*)d_in[1];
  const float* gcnb  = (const float*)d_in[2];
  const float* gateW = (const float*)d_in[3];
  const float* gateb = (const float*)d_in[4];
  const float* sew1  = (const float*)d_in[5];
  const float* seb1  = (const float*)d_in[6];
  const float* sew2  = (const float*)d_in[7];
  const float* seb2  = (const float*)d_in[8];
  const float* lng   = (const float*)d_in[9];
  const float* lnb   = (const float*)d_in[10];
  const float* Wih   = (const float*)d_in[11];
  const float* Whh   = (const float*)d_in[12];
  const float* bih   = (const float*)d_in[13];
  const float* bhh   = (const float*)d_in[14];
  const int* query   = (const int*)d_in[15];
  const int* support = (const int*)d_in[16];
  const int* qlc     = (const int*)d_in[17];
  const int* qrc     = (const int*)d_in[19];
  const int* slc     = (const int*)d_in[21];
  const int* src     = (const int*)d_in[23];
  const int* knn     = (const int*)d_in[25];
  float* out = (float*)d_out;

  float* w = (float*)d_ws;
  size_t o = 0;
  auto alloc = [&](size_t n) { float* p = w + o; o += (n + 15) & ~(size_t)15; return p; };
  float* xbuf      = alloc((size_t)2056*256);   // enc output: 2048 query rows + 5 support rows + 3 pad
  float* query_g   = alloc((size_t)2056*256);   // qenc output (rows 2048..2052 = se(supp))
  float* sg_hat    = alloc(256);
  float* z_supp    = alloc(1792);
  float* cbuf      = alloc((size_t)2048*512);
  float* Abuf      = alloc((size_t)2048*1792);
  float* Zbuf      = alloc((size_t)2048*1792);
  float* w1t       = alloc(256*512);
  float* w2t       = alloc(512*256);
  float* bias_s    = alloc(1792);
  ushort_t* A2     = (ushort_t*)alloc((size_t)2048*768/2);
  ushort_t* B2ih   = (ushort_t*)alloc((size_t)1792*768/2);
  ushort_t* B2hh   = (ushort_t*)alloc((size_t)1792*768/2);
  (void)ws_size; (void)in_sizes; (void)n_in; (void)out_size;

  // prep
  transpose_kernel<<<512,  256, 0, stream>>>(sew1, w1t, 512, 256, 0, 256);
  transpose_kernel<<<1024, 256, 0, stream>>>(sew2, w2t, 256, 512, 0, 512);
  build_b2t_kernel<<<1792, 256, 0, stream>>>(Wih, B2ih, 256);
  build_b2t_kernel<<<1792, 256, 0, stream>>>(Whh, B2hh, 512);
  bias_sum_kernel<<<7, 256, 0, stream>>>(bih, bhh, bias_s);

  // 1) neighbor encoders (query rows 0..2047, support rows 2048..2052 of xbuf)
  enc_kernel<<<4106, 256, 0, stream>>>(emb, gcnW, gcnb, gateW, gateb, knn,
                                       query, support, qlc, qrc, slc, src, xbuf);

  // 2) MLP+LN on all 2056 rows (query + support share the encoder), emits A2 for rows<2048
  qenc_kernel<<<257, 256, 0, stream>>>(xbuf, w1t, seb1, w2t, seb2, lng, lnb, query_g, A2);

  // 3) support aggregation: sg_hat + z_supp
  finalize_kernel<<<7, 256, 0, stream>>>(query_g, Whh, sg_hat, z_supp);

  // 4) LSTM matching with split-bf16 MFMA GEMMs (N=1792: o-gate tail unused)
  gemm_bf16_kernel<<<dim3(14,16), 256, 0, stream>>>(A2, B2ih, Abuf, nullptr, bias_s, 1792);
  gate_kernel<<<4096, 256, 0, stream>>>(Abuf, query_g, cbuf, A2, 1);
  for (int s = 1; s < 4; ++s) {
    gemm_bf16_kernel<<<dim3(14,16), 256, 0, stream>>>(A2, B2hh, Zbuf, Abuf, z_supp, 1792);
    if (s < 3) gate_kernel<<<4096, 256, 0, stream>>>(Zbuf, query_g, cbuf, A2, 0);
    else       gatecos_kernel<<<512, 256, 0, stream>>>(Zbuf, query_g, cbuf, sg_hat, out);
  }
}